// Round 1
// 952.439 us; speedup vs baseline: 1.3893x; 1.3893x over previous
//
#include <hip/hip_runtime.h>
#include <hip/hip_bf16.h>
#include <math.h>

// ---------------- problem constants ----------------
#define BIMG   4
#define CIN    512
#define MID    512
#define HF     50
#define WF     50
#define PIX    2500          // HF*WF
#define MTOT   10000         // BIMG*PIX
#define ANC    9
#define NLOC   22500         // PIX*ANC
#define NPRE   3000
#define NPOST  300
#define WORDS  47            // ceil(3000/64)
#define ROWPAD 3008
#define WSTRIDE 48           // padded words per NMS row
#define CAP    8192          // candidate capacity per image
#define KTOT   4608          // 9 taps * 512 channels
#define NSTEP  144           // KTOT / 32

// d_out layout (floats): rois, rois_idx, anchors, loc, bf_pred
#define ROIS_OFF 0
#define IDX_OFF  4800
#define ANC_OFF  6000
#define LOC_OFF  96000
#define BF_OFF   456000

#define RAWP_SZ   2560000UL                // 10000*64 f32

typedef _Float16 f16x8 __attribute__((ext_vector_type(8)));
typedef float f32x16 __attribute__((ext_vector_type(16)));

// Split f32 into (hi f16, lo f16*2^12) packed in u32: a ~= hi + lo*2^-12.
// Dropped product term al*bl contributes <= 2^-24*|ab| -> f32-ulp-level error.
__device__ __forceinline__ unsigned pack_split(float a) {
  _Float16 h = (_Float16)a;
  float r = a - (float)h;
  _Float16 l = (_Float16)(r * 4096.0f);
  unsigned short hb, lb;
  __builtin_memcpy(&hb, &h, 2);
  __builtin_memcpy(&lb, &l, 2);
  return (unsigned)hb | ((unsigned)lb << 16);
}

// ---------------- kernel 0: weight prep ----------------
// Wp[co*4608 + k] = split(conv_w[co][c][tap]),  k = tap*512 + c  (k-contig per co)
// W1t unchanged (f32, for the 1x1 heads).
__global__ __launch_bounds__(256) void prep_kernel(
    const float* __restrict__ conv_w, const float* __restrict__ loc_w,
    const float* __restrict__ bf_w, unsigned* __restrict__ Wp,
    float* __restrict__ W1t) {
  int o = blockIdx.x * 256 + threadIdx.x;
  if (o < 4608 * 512) {
    int co = o / 4608;
    int k  = o - co * 4608;
    int c   = k & 511;
    int tap = k >> 9;
    Wp[o] = pack_split(conv_w[(co * 512 + c) * 9 + tap]);
  } else {
    int o2 = o - 4608 * 512;
    if (o2 < 512 * 64) {
      int co = o2 & 63;
      int c  = o2 >> 6;
      float v = 0.0f;
      if (co < 36)      v = loc_w[co * 512 + c];
      else if (co < 54) v = bf_w[(co - 36) * 512 + c];
      W1t[o2] = v;
    }
  }
}

// ---------------- kernel 0b: input split-pack (pack path only) ----------------
__global__ __launch_bounds__(256) void packin_kernel(
    const float* __restrict__ in, unsigned* __restrict__ inp) {
  int i = blockIdx.x * 256 + threadIdx.x;
  if (i < BIMG * CIN * PIX) inp[i] = pack_split(in[i]);
}

// ---------------- kernel 1: 3x3 conv as f16-split MFMA implicit GEMM ----------------
// C[10000][512] = A[10000][4608] * W[4608][512], A = im2col of input.
// Block = 128(M) x 64(N), 4 waves (2x2), wave-tile 64x32 via two 32x32x16 f16 MFMAs.
// 3 MFMA passes/step: acc0 += ah*bh ; acc1 += ah*bl + al*bh ; out = acc0 + acc1/4096.
// LDS: planes Ah(128x64B) Al Bh(64x64B) Bl per buffer, XOR slot-swizzle
// (slot ^= (row>>2)&3) -> conflict-free b128 reads/writes. Double-buffered.
#define LDS_AL 8192
#define LDS_BH 16384
#define LDS_BL 20480
#define LDS_BUF 24576

#define FETCH(st_) do {                                                        \
  int k0_ = (st_) * 32;                                                        \
  int tap_ = k0_ >> 9;                                                         \
  int c0_ = k0_ & 511;                                                         \
  int t3_ = tap_ / 3;                                                          \
  int dy_ = t3_ - 1, dx_ = tap_ - 3 * t3_ - 1;                                 \
  int iy_ = yy + dy_, ix_ = xx + dx_;                                          \
  bool ok_ = qv && ((unsigned)iy_ < (unsigned)HF) &&                           \
             ((unsigned)ix_ < (unsigned)WF);                                   \
  int off_ = iy_ * WF + ix_;                                                   \
  if (USEPACK) {                                                               \
    const unsigned* ap_ = apack + (size_t)c0_ * PIX;                           \
    _Pragma("unroll") for (int j_ = 0; j_ < 16; ++j_)                          \
      av[j_] = ok_ ? ap_[off_ + j_ * PIX] : 0u;                                \
  } else {                                                                     \
    const float* ap_ = afl + (size_t)c0_ * PIX;                                \
    _Pragma("unroll") for (int j_ = 0; j_ < 16; ++j_)                          \
      av[j_] = ok_ ? pack_split(ap_[off_ + j_ * PIX]) : 0u;                    \
  }                                                                            \
  const unsigned* wp_ = wbase + k0_;                                           \
  wq0 = *(const uint4*)(wp_);                                                  \
  wq1 = *(const uint4*)(wp_ + 4);                                              \
} while (0)

#define STORE_LDS(buf_) do {                                                   \
  unsigned h0=(av[0]&0xFFFFu)|(av[1]<<16),  h1=(av[2]&0xFFFFu)|(av[3]<<16);    \
  unsigned h2=(av[4]&0xFFFFu)|(av[5]<<16),  h3=(av[6]&0xFFFFu)|(av[7]<<16);    \
  unsigned h4=(av[8]&0xFFFFu)|(av[9]<<16),  h5=(av[10]&0xFFFFu)|(av[11]<<16);  \
  unsigned h6=(av[12]&0xFFFFu)|(av[13]<<16),h7=(av[14]&0xFFFFu)|(av[15]<<16);  \
  unsigned l0=(av[0]>>16)|(av[1]&0xFFFF0000u),                                 \
           l1=(av[2]>>16)|(av[3]&0xFFFF0000u);                                 \
  unsigned l2=(av[4]>>16)|(av[5]&0xFFFF0000u),                                 \
           l3=(av[6]>>16)|(av[7]&0xFFFF0000u);                                 \
  unsigned l4=(av[8]>>16)|(av[9]&0xFFFF0000u),                                 \
           l5=(av[10]>>16)|(av[11]&0xFFFF0000u);                               \
  unsigned l6=(av[12]>>16)|(av[13]&0xFFFF0000u),                               \
           l7=(av[14]>>16)|(av[15]&0xFFFF0000u);                               \
  char* bp_ = (char*)&lds[buf_][0];                                            \
  const int swA_ = (px >> 2) & 3;                                              \
  *(uint4*)(bp_ + px*64 + (((2*kg+0)^swA_)<<4)) = make_uint4(h0,h1,h2,h3);     \
  *(uint4*)(bp_ + px*64 + (((2*kg+1)^swA_)<<4)) = make_uint4(h4,h5,h6,h7);     \
  *(uint4*)(bp_ + LDS_AL + px*64 + (((2*kg+0)^swA_)<<4)) =                     \
      make_uint4(l0,l1,l2,l3);                                                 \
  *(uint4*)(bp_ + LDS_AL + px*64 + (((2*kg+1)^swA_)<<4)) =                     \
      make_uint4(l4,l5,l6,l7);                                                 \
  unsigned wh0=(wq0.x&0xFFFFu)|(wq0.y<<16), wh1=(wq0.z&0xFFFFu)|(wq0.w<<16);   \
  unsigned wh2=(wq1.x&0xFFFFu)|(wq1.y<<16), wh3=(wq1.z&0xFFFFu)|(wq1.w<<16);   \
  unsigned wl0=(wq0.x>>16)|(wq0.y&0xFFFF0000u),                                \
           wl1=(wq0.z>>16)|(wq0.w&0xFFFF0000u);                                \
  unsigned wl2=(wq1.x>>16)|(wq1.y&0xFFFF0000u),                                \
           wl3=(wq1.z>>16)|(wq1.w&0xFFFF0000u);                                \
  const int swB_ = (bcol >> 2) & 3;                                            \
  *(uint4*)(bp_ + LDS_BH + bcol*64 + ((kg2^swB_)<<4)) =                        \
      make_uint4(wh0,wh1,wh2,wh3);                                             \
  *(uint4*)(bp_ + LDS_BL + bcol*64 + ((kg2^swB_)<<4)) =                        \
      make_uint4(wl0,wl1,wl2,wl3);                                             \
} while (0)

template <int USEPACK>
__global__ __launch_bounds__(256, 3) void conv3x3_kernel(
    const float* __restrict__ inf, const unsigned* __restrict__ inp,
    const unsigned* __restrict__ Wp, float* __restrict__ part0) {
  __shared__ __align__(16) unsigned char lds[2][LDS_BUF];

  const int tid = threadIdx.x;
  const int lane = tid & 63;
  const int wid = tid >> 6;
  const int wr = wid >> 1, wc = wid & 1;

  // 632 = 79 M-blocks x 8 N-blocks; XCD-chunk swizzle: each XCD owns one
  // N-block's full M sweep -> its 1.18 MB W-slice stays L2-resident.
  int flat = blockIdx.x;
  int sblk = (flat & 7) * 79 + (flat >> 3);
  int nb = sblk / 79;
  int mb = sblk - nb * 79;
  const int m0 = mb * 128;
  const int n0 = nb * 64;

  // staging geometry
  const int px  = tid & 127;          // A row (tile pixel)
  const int kg  = tid >> 7;           // A: two 16-channel groups
  const int bcol = tid & 63;          // B col
  const int kg2 = tid >> 6;           // B: four 8-k groups

  const int q = m0 + px;
  const bool qv = q < MTOT;
  const int qq = qv ? q : 0;
  const int bi = qq / PIX;
  const int rr = qq - bi * PIX;
  const int yy = rr / WF;
  const int xx = rr - yy * WF;
  const unsigned* __restrict__ apack =
      inp + (size_t)bi * (CIN * PIX) + (size_t)(kg * 16) * PIX;
  const float* __restrict__ afl =
      inf + (size_t)bi * (CIN * PIX) + (size_t)(kg * 16) * PIX;
  const unsigned* __restrict__ wbase =
      Wp + (size_t)(n0 + bcol) * KTOT + kg2 * 8;

  f32x16 acc0[2], acc1[2];
#pragma unroll
  for (int i = 0; i < 2; ++i)
#pragma unroll
    for (int r = 0; r < 16; ++r) { acc0[i][r] = 0.0f; acc1[i][r] = 0.0f; }

  unsigned av[16];
  uint4 wq0, wq1;

  FETCH(0);
  STORE_LDS(0);
  __syncthreads();

  int cur = 0;
#pragma unroll 1
  for (int st = 0; st < NSTEP; ++st) {
    const bool hn = (st + 1) < NSTEP;
    if (hn) FETCH(st + 1);

    // compute on lds[cur]
    {
      const char* base = (const char*)&lds[cur][0];
      const int g = lane >> 5;
      const int ar0 = wr * 64 + (lane & 31);
      const int ar1 = ar0 + 32;
      const int br  = wc * 32 + (lane & 31);
      const int swa = (ar0 >> 2) & 3;   // same for ar1 (+32 doesn't change bits 3:2)
      const int swb = (br >> 2) & 3;
#pragma unroll
      for (int h = 0; h < 2; ++h) {
        const int sb = 2 * h + g;
        f16x8 a0h = *(const f16x8*)(base + ar0 * 64 + ((sb ^ swa) << 4));
        f16x8 a1h = *(const f16x8*)(base + ar1 * 64 + ((sb ^ swa) << 4));
        f16x8 a0l = *(const f16x8*)(base + LDS_AL + ar0 * 64 + ((sb ^ swa) << 4));
        f16x8 a1l = *(const f16x8*)(base + LDS_AL + ar1 * 64 + ((sb ^ swa) << 4));
        f16x8 bh  = *(const f16x8*)(base + LDS_BH + br * 64 + ((sb ^ swb) << 4));
        f16x8 bl  = *(const f16x8*)(base + LDS_BL + br * 64 + ((sb ^ swb) << 4));
        acc0[0] = __builtin_amdgcn_mfma_f32_32x32x16_f16(a0h, bh, acc0[0], 0, 0, 0);
        acc0[1] = __builtin_amdgcn_mfma_f32_32x32x16_f16(a1h, bh, acc0[1], 0, 0, 0);
        acc1[0] = __builtin_amdgcn_mfma_f32_32x32x16_f16(a0h, bl, acc1[0], 0, 0, 0);
        acc1[0] = __builtin_amdgcn_mfma_f32_32x32x16_f16(a0l, bh, acc1[0], 0, 0, 0);
        acc1[1] = __builtin_amdgcn_mfma_f32_32x32x16_f16(a1h, bl, acc1[1], 0, 0, 0);
        acc1[1] = __builtin_amdgcn_mfma_f32_32x32x16_f16(a1l, bh, acc1[1], 0, 0, 0);
      }
    }

    if (hn) STORE_LDS(cur ^ 1);
    __syncthreads();
    cur ^= 1;
  }

  // epilogue: C/D layout (32x32): col = lane&31, row = (r&3) + 8*(r>>2) + 4*(lane>>5)
  const int colg = n0 + wc * 32 + (lane & 31);
  const int rbase = m0 + wr * 64 + 4 * (lane >> 5);
#pragma unroll
  for (int i = 0; i < 2; ++i) {
#pragma unroll
    for (int r = 0; r < 16; ++r) {
      int rowg = rbase + i * 32 + (r & 3) + 8 * (r >> 2);
      if (rowg < MTOT)
        part0[(size_t)rowg * 512 + colg] =
            (float)((double)acc0[i][r] + (double)acc1[i][r] * (1.0 / 4096.0));
    }
  }
}

// ---------------- kernel 2: 1x1 heads, 64-pixel tile (unchanged; nz=1 now) ----------------
__global__ __launch_bounds__(256) void conv1x1_kernel(
    const float* __restrict__ p0, const float* __restrict__ p1,
    const float* __restrict__ p2, const float* __restrict__ p3, int nz,
    const float* __restrict__ convb, const float* __restrict__ W1t,
    float* __restrict__ rawp0, float* __restrict__ rawp1,
    float* __restrict__ rawp2, float* __restrict__ rawp3) {
  __shared__ float As[16][64];
  const int tid = threadIdx.x;
  const int q0 = blockIdx.x * 64;
  const int by = blockIdx.y;
  const int lane = tid & 63;
  const int wv = tid >> 6;
  const int col0 = __builtin_amdgcn_readfirstlane(wv * 16);   // 4 waves x 16 = 64 cols
  float* __restrict__ rp = (by == 0) ? rawp0 : (by == 1) ? rawp1 :
                           (by == 2) ? rawp2 : rawp3;

  const int sg = tid >> 6;
  const int sp = tid & 63;
  const int qs = q0 + sp;
  const bool okL = qs < MTOT;

  double acc[16];
  float accf[16];
#pragma unroll
  for (int c = 0; c < 16; ++c) { acc[c] = 0.0; accf[c] = 0.0f; }

  for (int kbl = 0; kbl < 8; ++kbl) {
    int kb = by * 8 + kbl;
    int c0 = kb * 16;
    float fv[4] = {0.0f, 0.0f, 0.0f, 0.0f};
    if (okL) {
      const size_t base = (size_t)qs * 512 + c0 + sg * 4;
      double s[4];
      float4 a0 = *(const float4*)&p0[base];
      s[0] = (double)a0.x; s[1] = (double)a0.y; s[2] = (double)a0.z; s[3] = (double)a0.w;
      if (nz > 1) {
        float4 b0 = *(const float4*)&p1[base];
        s[0] += (double)b0.x; s[1] += (double)b0.y; s[2] += (double)b0.z; s[3] += (double)b0.w;
      }
      if (nz > 2) {
        float4 c0v = *(const float4*)&p2[base];
        s[0] += (double)c0v.x; s[1] += (double)c0v.y; s[2] += (double)c0v.z; s[3] += (double)c0v.w;
        float4 d0 = *(const float4*)&p3[base];
        s[0] += (double)d0.x; s[1] += (double)d0.y; s[2] += (double)d0.z; s[3] += (double)d0.w;
      }
      float4 bsv = *(const float4*)&convb[c0 + sg * 4];
      fv[0] = (float)fmax(s[0] + (double)bsv.x, 0.0);
      fv[1] = (float)fmax(s[1] + (double)bsv.y, 0.0);
      fv[2] = (float)fmax(s[2] + (double)bsv.z, 0.0);
      fv[3] = (float)fmax(s[3] + (double)bsv.w, 0.0);
    }
    __syncthreads();
#pragma unroll
    for (int j = 0; j < 4; ++j) As[sg * 4 + j][sp] = fv[j];
    __syncthreads();

    const float* __restrict__ Bw = W1t + (size_t)c0 * 64 + col0;
#pragma unroll
    for (int kk = 0; kk < 16; ++kk) {
      const float* __restrict__ br = Bw + (size_t)kk * 64;
      float a = As[kk][lane];
#pragma unroll
      for (int c = 0; c < 16; ++c)
        accf[c] = fmaf(a, br[c], accf[c]);   // br[c] wave-uniform -> scalar
    }
    if (kbl & 1) {                 // fold every 2 kb (32-MAC chains)
#pragma unroll
      for (int c = 0; c < 16; ++c) {
        acc[c] += (double)accf[c];
        accf[c] = 0.0f;
      }
    }
  }

  int q = q0 + lane;
  if (q < MTOT) {
    float o[16];
#pragma unroll
    for (int c = 0; c < 16; ++c) o[c] = (float)acc[c];
    float* fp = &rp[(size_t)q * 64 + col0];
#pragma unroll
    for (int g = 0; g < 4; ++g)
      *(float4*)&fp[g * 4] = make_float4(o[g*4], o[g*4+1], o[g*4+2], o[g*4+3]);
  }
}

// ---------------- kernel 3: epilogue — sum rawp + head bias (f64), softmax/decode/clip, u64 keys ----------------
__global__ __launch_bounds__(256) void epilogue_kernel(
    const float* __restrict__ r0, const float* __restrict__ r1,
    const float* __restrict__ r2, const float* __restrict__ r3,
    const float* __restrict__ locb, const float* __restrict__ bfb,
    float* __restrict__ d_out, double* __restrict__ boxd,
    unsigned long long* __restrict__ ukey,
    const int* __restrict__ imh, const int* __restrict__ imw) {
  int idx = blockIdx.x * 256 + threadIdx.x;
  if (idx >= BIMG * NLOC) return;
  int b = idx / NLOC;
  int i = idx - b * NLOC;
  int p = i / ANC;
  int a = i - p * ANC;
  int y = p / WF;
  int x = p - y * WF;
  int q = b * PIX + p;
  const size_t rb = (size_t)q * 64;

  // loc: co = a*4 .. a*4+3, bias = locb
  float4 A0 = *(const float4*)&r0[rb + a * 4];
  float4 A1 = *(const float4*)&r1[rb + a * 4];
  float4 A2 = *(const float4*)&r2[rb + a * 4];
  float4 A3 = *(const float4*)&r3[rb + a * 4];
  double l0d = (((double)A0.x + (double)A1.x) + (double)A2.x) + (double)A3.x + (double)locb[a * 4 + 0];
  double l1d = (((double)A0.y + (double)A1.y) + (double)A2.y) + (double)A3.y + (double)locb[a * 4 + 1];
  double l2d = (((double)A0.z + (double)A1.z) + (double)A2.z) + (double)A3.z + (double)locb[a * 4 + 2];
  double l3d = (((double)A0.w + (double)A1.w) + (double)A2.w) + (double)A3.w + (double)locb[a * 4 + 3];
  *(float4*)&d_out[LOC_OFF + (size_t)idx * 4] =
      make_float4((float)l0d, (float)l1d, (float)l2d, (float)l3d);

  // logits: co = 36+2a, 37+2a, bias = bfb
  float2 G0 = *(const float2*)&r0[rb + 36 + a * 2];
  float2 G1 = *(const float2*)&r1[rb + 36 + a * 2];
  float2 G2 = *(const float2*)&r2[rb + 36 + a * 2];
  float2 G3 = *(const float2*)&r3[rb + 36 + a * 2];
  double g0 = (((double)G0.x + (double)G1.x) + (double)G2.x) + (double)G3.x + (double)bfb[a * 2 + 0];
  double g1 = (((double)G0.y + (double)G1.y) + (double)G2.y) + (double)G3.y + (double)bfb[a * 2 + 1];
  double m  = fmax(g0, g1);
  double e0 = exp(g0 - m), e1 = exp(g1 - m);
  double s  = e0 + e1;
  double p0 = e0 / s, p1 = e1 / s;
  *(float2*)&d_out[BF_OFF + (size_t)idx * 2] = make_float2((float)p0, (float)p1);

  // anchor (f64)
  int ridx = a / 3, sidx = a - ridx * 3;
  double ratio = (ridx == 0) ? 0.5 : ((ridx == 1) ? 1.0 : 2.0);
  double scale = (sidx == 0) ? 8.0 : ((sidx == 1) ? 16.0 : 32.0);
  double hs = 16.0 * scale * sqrt(ratio);
  double ws = 16.0 * scale * sqrt(1.0 / ratio);
  double sy = (double)(y * 16), sx = (double)(x * 16);
  double a0 = sy + (8.0 - hs * 0.5);
  double a1 = sx + (8.0 - ws * 0.5);
  double a2 = sy + (8.0 + hs * 0.5);
  double a3 = sx + (8.0 + ws * 0.5);
  if (b == 0) {
    *(float4*)&d_out[ANC_OFF + (size_t)i * 4] =
        make_float4((float)a0, (float)a1, (float)a2, (float)a3);
  }

  // decode + clip (f64)
  double ah = a2 - a0, aw = a3 - a1;
  double acy = a0 + 0.5 * ah, acx = a1 + 0.5 * aw;
  double cy = l0d * ah + acy;
  double cx = l1d * aw + acx;
  double hh = exp(l2d) * ah;
  double ww = exp(l3d) * aw;
  double ihf = (double)imh[0], iwf = (double)imw[0];
  double b0 = fmin(fmax(cy - 0.5 * hh, 0.0), ihf);
  double b1 = fmin(fmax(cx - 0.5 * ww, 0.0), iwf);
  double b2 = fmin(fmax(cy + 0.5 * hh, 0.0), ihf);
  double b3 = fmin(fmax(cx + 0.5 * ww, 0.0), iwf);
  double* bp = &boxd[(size_t)idx * 4];
  bp[0] = b0; bp[1] = b1; bp[2] = b2; bp[3] = b3;

  bool valid = (b2 - b0 >= 16.0) && (b3 - b1 >= 16.0);
  double d = valid ? (g1 - g0) : -INFINITY;
  long long bits = __double_as_longlong(d);
  unsigned long long u = (bits < 0)
      ? ~(unsigned long long)bits
      : ((unsigned long long)bits | 0x8000000000000000ull);
  ukey[idx] = ~u;   // smaller key = better rank
}

// ---------------- kernel 4a: histogram -> threshold bin + candidate compaction ----------------
__global__ __launch_bounds__(1024) void thresh_kernel(
    const unsigned long long* __restrict__ ukey,
    unsigned* __restrict__ ccnt, unsigned* __restrict__ cand) {
  __shared__ unsigned hist[16384];
  __shared__ unsigned csum[1024];
  __shared__ unsigned sT, scnt;
  int b = blockIdx.x;
  int tid = threadIdx.x;
  for (int i = tid; i < 16384; i += 1024) hist[i] = 0;
  if (tid == 0) scnt = 0;
  __syncthreads();
  for (int j = tid; j < NLOC; j += 1024)
    atomicAdd(&hist[(unsigned)(ukey[(size_t)b * NLOC + j] >> 50)], 1u);
  __syncthreads();
  unsigned s = 0;
#pragma unroll
  for (int k = 0; k < 16; ++k) s += hist[tid * 16 + k];
  csum[tid] = s;
  __syncthreads();
  if (tid == 0) {
    unsigned cum = 0;
    int T = 16383;
    for (int c = 0; c < 1024; ++c) {
      if (cum + csum[c] >= NPRE) {
        unsigned cc = cum;
        for (int k = 0; k < 16; ++k) {
          cc += hist[c * 16 + k];
          if (cc >= NPRE) { T = c * 16 + k; break; }
        }
        break;
      }
      cum += csum[c];
    }
    sT = (unsigned)T;
  }
  __syncthreads();
  unsigned T = sT;
  for (int j = tid; j < NLOC; j += 1024) {
    if ((unsigned)(ukey[(size_t)b * NLOC + j] >> 50) <= T) {
      unsigned slot = atomicAdd(&scnt, 1u);
      if (slot < CAP) cand[(size_t)b * CAP + slot] = (unsigned)j;
    }
  }
  __syncthreads();
  if (tid == 0) ccnt[b] = scnt;
}

// ---------------- kernel 4b: exact rank among candidates -> sb ----------------
__global__ __launch_bounds__(256) void rank_kernel(
    const unsigned long long* __restrict__ ukey, const unsigned* __restrict__ ccnt,
    const unsigned* __restrict__ cand, const double* __restrict__ boxd,
    double* __restrict__ sbd) {
  __shared__ unsigned long long kt[256];
  __shared__ unsigned it[256];
  int b = blockIdx.y;
  int C = (int)min(ccnt[b], (unsigned)CAP);
  int s = blockIdx.x * 256 + threadIdx.x;
  bool act = s < C;
  unsigned myi = act ? cand[(size_t)b * CAP + s] : 0xFFFFFFFFu;
  unsigned long long ki = act ? ukey[(size_t)b * NLOC + myi] : ~0ull;
  int cnt = 0;
  int ntile = (C + 255) >> 8;
  for (int t = 0; t < ntile; ++t) {
    int j = t * 256 + threadIdx.x;
    unsigned ji = (j < C) ? cand[(size_t)b * CAP + j] : 0xFFFFFFFFu;
    kt[threadIdx.x] = (j < C) ? ukey[(size_t)b * NLOC + ji] : ~0ull;
    it[threadIdx.x] = ji;
    __syncthreads();
#pragma unroll 8
    for (int jj = 0; jj < 256; ++jj) {
      unsigned long long kj = kt[jj];
      unsigned jidx = it[jj];
      cnt += ((kj < ki) || (kj == ki && jidx < myi)) ? 1 : 0;
    }
    __syncthreads();
  }
  if (act && cnt < NPRE) {
    const double* bx = &boxd[((size_t)b * NLOC + myi) * 4];
    double* dp = &sbd[((size_t)b * NPRE + cnt) * 4];
    dp[0] = bx[0]; dp[1] = bx[1]; dp[2] = bx[2]; dp[3] = bx[3];
  }
}

// ---------------- kernel 5: NMS suppression bitmask matrix (f64 IoU) ----------------
__global__ __launch_bounds__(64) void nmsmask_kernel(
    const double* __restrict__ sbd, unsigned long long* __restrict__ M) {
  __shared__ double cb[64][4];
  int b = blockIdx.z;
  int jw = blockIdx.y;
  int i  = blockIdx.x * 64 + threadIdx.x;
  int j  = jw * 64 + threadIdx.x;
  double j0 = 0, j1 = 0, j2 = 0, j3 = 0;
  if (j < NPRE) {
    const double* bp = &sbd[((size_t)b * NPRE + j) * 4];
    j0 = bp[0]; j1 = bp[1]; j2 = bp[2]; j3 = bp[3];
  }
  cb[threadIdx.x][0] = j0; cb[threadIdx.x][1] = j1;
  cb[threadIdx.x][2] = j2; cb[threadIdx.x][3] = j3;
  __syncthreads();
  if (i >= NPRE) return;
  const double* bp = &sbd[((size_t)b * NPRE + i) * 4];
  double i0 = bp[0], i1 = bp[1], i2 = bp[2], i3 = bp[3];
  double ai = (i2 - i0) * (i3 - i1);
  unsigned long long mask = 0ull;
#pragma unroll 4
  for (int t = 0; t < 64; ++t) {
    double aj = (cb[t][2] - cb[t][0]) * (cb[t][3] - cb[t][1]);
    double h = fmax(fmin(i2, cb[t][2]) - fmax(i0, cb[t][0]), 0.0);
    double w = fmax(fmin(i3, cb[t][3]) - fmax(i1, cb[t][1]), 0.0);
    double inter = h * w;
    double iou = inter / (ai + aj - inter + 1e-9);
    mask |= ((iou > 0.7) ? 1ull : 0ull) << t;
  }
  M[((size_t)b * ROWPAD + i) * WSTRIDE + jw] = mask;
}

// ---------------- kernel 6: sequential NMS scan (1 wave / image) ----------------
__global__ __launch_bounds__(64) void nms_scan_kernel(
    const double* __restrict__ sbd, const unsigned long long* __restrict__ M,
    float* __restrict__ d_out) {
  int b = blockIdx.x;
  int lane = threadIdx.x;
  for (int k = lane; k < NPOST; k += 64) {
    *(float4*)&d_out[ROIS_OFF + (size_t)(b * NPOST + k) * 4] = make_float4(0, 0, 0, 0);
    d_out[IDX_OFF + b * NPOST + k] = (float)b;
  }
  __syncthreads();

  unsigned long long R = ~0ull;
  if (lane < WORDS) R = 0ull;
  for (int w = 0; w < WORDS; ++w) {
    int j = w * 64 + lane;
    bool inval = true;
    if (j < NPRE) {
      const double* bp = &sbd[((size_t)b * NPRE + j) * 4];
      double h = bp[2] - bp[0], wd = bp[3] - bp[1];
      inval = !(h >= 16.0 && wd >= 16.0);
    }
    unsigned long long bal = __ballot(inval ? 1 : 0);
    if (lane == w) R |= bal;
  }

  int kept = 0;
  while (kept < NPOST) {
    unsigned long long hz = __ballot(((~R) != 0ull) ? 1 : 0);
    if (hz == 0ull) break;
    int w0 = __ffsll(hz) - 1;
    unsigned long long word = __shfl(R, w0);
    int bit = __ffsll(~word) - 1;
    int i = w0 * 64 + bit;
    if (lane < 4)
      d_out[ROIS_OFF + (size_t)(b * NPOST + kept) * 4 + lane] =
          (float)sbd[((size_t)b * NPRE + i) * 4 + lane];
    kept++;
    if (kept >= NPOST) break;
    unsigned long long row = (lane < WORDS)
        ? M[((size_t)b * ROWPAD + i) * WSTRIDE + lane] : 0ull;
    R |= row;
    if (lane == w0) R |= (1ull << bit);
  }
}

// ---------------- launch ----------------
extern "C" void kernel_launch(void* const* d_in, const int* in_sizes, int n_in,
                              void* d_out, int out_size, void* d_ws, size_t ws_size,
                              hipStream_t stream) {
  const float* in     = (const float*)d_in[0];
  const float* conv_w = (const float*)d_in[1];
  const float* conv_b = (const float*)d_in[2];
  const float* bf_w   = (const float*)d_in[3];
  const float* bf_b   = (const float*)d_in[4];
  const float* loc_w  = (const float*)d_in[5];
  const float* loc_b  = (const float*)d_in[6];
  const int*   imh    = (const int*)d_in[7];
  const int*   imw    = (const int*)d_in[8];
  float* out = (float*)d_out;

  char* ws = (char*)d_ws;

  // Workspace layouts (bytes). Pack path needs 54,512,256; fallback fits the
  // old nz=1 footprint (36,592,256) so any previously-working ws_size is safe.
  const bool usep = ws_size >= 54512256UL;
  size_t o_wp = 0, o_w1t = 9437184UL;
  size_t o_inpk, o_feat, o_score, o_boxd, o_sbd, o_m, o_cand, o_cnt, o_rawp3;
  if (usep) {
    o_inpk  = 9568256UL;
    o_feat  = 30048256UL;
    o_score = 50528256UL;
    o_boxd  = 51248256UL;
    o_sbd   = 54128256UL;
    o_m     = o_inpk;                    // in_pack dead after conv3x3
    o_cand  = o_inpk + 4620288UL;
    o_cnt   = o_cand + 131072UL;
    o_rawp3 = o_m;
  } else {
    o_inpk  = 0;                         // unused
    o_feat  = 9568256UL;
    o_score = 30048256UL;
    o_boxd  = 30768256UL;
    o_sbd   = 33648256UL;
    o_rawp3 = 34032256UL;
    o_m     = o_feat;                    // part0 dead after conv1x1
    o_cand  = o_feat + 4620288UL;
    o_cnt   = o_cand + 131072UL;
  }

  unsigned* Wp   = (unsigned*)(ws + o_wp);
  float*    W1t  = (float*)(ws + o_w1t);
  unsigned* inpk = (unsigned*)(ws + (usep ? o_inpk : o_wp));  // dummy ptr if unused
  float*    part0 = (float*)(ws + o_feat);
  unsigned long long* ukey = (unsigned long long*)(ws + o_score);
  double*   boxd = (double*)(ws + o_boxd);
  double*   sbd  = (double*)(ws + o_sbd);
  unsigned long long* M = (unsigned long long*)(ws + o_m);
  unsigned* cand = (unsigned*)(ws + o_cand);
  unsigned* ccnt = (unsigned*)(ws + o_cnt);
  // head-GEMM partials: reclaim Wp (dead after conv3x3) + M region
  float* rawp0 = (float*)(ws + o_wp);
  float* rawp1 = (float*)(ws + o_wp + RAWP_SZ);
  float* rawp2 = (float*)(ws + o_wp + 2 * RAWP_SZ);
  float* rawp3 = (float*)(ws + o_rawp3);

  hipLaunchKernelGGL(prep_kernel, dim3((4608 * 512 + 512 * 64 + 255) / 256), dim3(256),
                     0, stream, conv_w, loc_w, bf_w, Wp, W1t);
  if (usep) {
    hipLaunchKernelGGL(packin_kernel, dim3((BIMG * CIN * PIX + 255) / 256), dim3(256),
                       0, stream, in, inpk);
    hipLaunchKernelGGL((conv3x3_kernel<1>), dim3(632), dim3(256), 0, stream,
                       in, (const unsigned*)inpk, (const unsigned*)Wp, part0);
  } else {
    hipLaunchKernelGGL((conv3x3_kernel<0>), dim3(632), dim3(256), 0, stream,
                       in, (const unsigned*)Wp, (const unsigned*)Wp, part0);
  }
  hipLaunchKernelGGL(conv1x1_kernel, dim3(157, 4), dim3(256), 0, stream,
                     part0, part0, part0, part0, 1, conv_b, W1t,
                     rawp0, rawp1, rawp2, rawp3);
  hipLaunchKernelGGL(epilogue_kernel, dim3((BIMG * NLOC + 255) / 256), dim3(256), 0, stream,
                     rawp0, rawp1, rawp2, rawp3, loc_b, bf_b, out, boxd, ukey, imh, imw);
  hipLaunchKernelGGL(thresh_kernel, dim3(4), dim3(1024), 0, stream, ukey, ccnt, cand);
  hipLaunchKernelGGL(rank_kernel, dim3(CAP / 256, 4), dim3(256), 0, stream,
                     ukey, ccnt, cand, boxd, sbd);
  hipLaunchKernelGGL(nmsmask_kernel, dim3(47, 47, 4), dim3(64), 0, stream, sbd, M);
  hipLaunchKernelGGL(nms_scan_kernel, dim3(4), dim3(64), 0, stream, sbd, M, out);
}